// Round 15
// baseline (240.333 us; speedup 1.0000x reference)
//
#include <hip/hip_runtime.h>
#include <hip/hip_bf16.h>

#define DEV static __device__ __forceinline__

typedef __attribute__((ext_vector_type(4))) float f32x4;
typedef __attribute__((ext_vector_type(8))) short bf16x8;
typedef __attribute__((ext_vector_type(8))) _Float16 half8;
typedef __attribute__((ext_vector_type(2))) _Float16 half2v;
typedef __attribute__((ext_vector_type(8))) unsigned short u16x8;

#define ESTRIDE 10240   // edges per bucket region in ebuf (Poisson(6250)+45sd)

DEV float leakys(float v) { return v > 0.f ? v : 0.2f * v; }
DEV float4 add4(float4 a, float4 b) { return make_float4(a.x+b.x, a.y+b.y, a.z+b.z, a.w+b.w); }
DEV float4 leaky4(float4 v) { return make_float4(leakys(v.x), leakys(v.y), leakys(v.z), leakys(v.w)); }
DEV float4 exp4(float4 v) { return make_float4(__expf(v.x), __expf(v.y), __expf(v.z), __expf(v.w)); }
DEV float pick4(float4 v, int i) {
    float r = v.x;
    r = (i == 1) ? v.y : r;
    r = (i == 2) ? v.z : r;
    r = (i == 3) ? v.w : r;
    return r;
}

DEV ushort f2bf(float f) {
    union { float f; unsigned u; } v; v.f = f;
    unsigned u = v.u;
    unsigned r = (u + 0x7FFFu + ((u >> 16) & 1u)) >> 16;   // RNE
    return (ushort)r;
}
DEV float bf2f(ushort h) {
    union { unsigned u; float f; } v; v.u = ((unsigned)h) << 16;
    return v.f;
}
DEV ushort f2h(float f) {
    union { _Float16 h; ushort u; } v;
    v.h = (_Float16)f;
    return v.u;
}
DEV half2v u2h2(ushort2 u) {
    union { ushort2 u; half2v h; } v; v.u = u;
    return v.h;
}

// ---------------------------------------------------------------------------
// One-time W1 prep: W[K=128][128] f32 -> transposed bf16 hi/lo  Wt[n][k].
// ---------------------------------------------------------------------------
__global__ void prep_w(const float* __restrict__ W, ushort* __restrict__ Wth,
                       ushort* __restrict__ Wtl, int NC) {
    int i = blockIdx.x * 256 + threadIdx.x;
    if (i >= 128 * NC) return;
    int k = i / NC, n = i % NC;
    float v = W[i];
    ushort hi = f2bf(v);
    ushort lo = f2bf(v - bf2f(hi));
    Wth[n * 128 + k] = hi;
    Wtl[n * 128 + k] = lo;
}

// W2 prep: f32 [128][64] -> fp16 transposed, stride 130 (2-way LDS aliasing)
__global__ void prep_w2h(const float* __restrict__ W2, ushort* __restrict__ W2t) {
    int i = blockIdx.x * 256 + threadIdx.x;
    if (i >= 64 * 128) return;
    int c = i >> 7, k = i & 127;
    W2t[c * 130 + k] = f2h(W2[k * 64 + c]);
}

// ---------------------------------------------------------------------------
// MFMA GEMM (layer 1 only): C16 = fp16(A @ W1), fused attdot (H=4).
// Heterogeneous grid: blocks >= nGemmBlocks run the bucket scatter.
// ---------------------------------------------------------------------------
template <int NCOLS, bool AH>
__launch_bounds__(256, 2)
__global__ void gemm_mfma(const float* __restrict__ A, const ushort* __restrict__ A16,
                          const ushort* __restrict__ Wth, const ushort* __restrict__ Wtl,
                          ushort* __restrict__ C16,
                          const float* __restrict__ att_s, const float* __restrict__ att_d,
                          float* __restrict__ as_out, float* __restrict__ ad_out, int N,
                          const int* __restrict__ srcIdx, const int* __restrict__ dstIdx,
                          int* __restrict__ bcursor, uint2* __restrict__ ebuf,
                          int E, int nGemmBlocks) {
    constexpr int NT = NCOLS / 64;          // 16-wide n-tiles per wave
    __shared__ ushort Xhi[64 * 128];
    __shared__ ushort Xlo[64 * 128];
    const int t = threadIdx.x;

    if (blockIdx.x >= nGemmBlocks) {       // ---- fused bscatter path ----
        __shared__ int hist[256];
        __shared__ int gofs[256];
        hist[t] = 0;
        __syncthreads();
        int blk = blockIdx.x - nGemmBlocks;
        int e0 = blk * 4096;
        int e1 = min(E, e0 + 4096);
        for (int e = e0 + t; e < e1; e += 256)
            atomicAdd(&hist[dstIdx[e] >> 9], 1);
        __syncthreads();
        int h = hist[t];
        if (h) gofs[t] = atomicAdd(&bcursor[t], h);
        __syncthreads();
        hist[t] = 0;
        __syncthreads();
        for (int e = e0 + t; e < e1; e += 256) {
            int d = dstIdx[e];
            int b = d >> 9;
            int r = atomicAdd(&hist[b], 1);
            uint2 v; v.x = (unsigned)srcIdx[e]; v.y = (unsigned)d;
            ebuf[(size_t)b * ESTRIDE + gofs[b] + r] = v;
        }
        return;
    }

    const int wv = t >> 6, l = t & 63;
    const int l15 = l & 15, lhi = l >> 4;
    const int row0 = blockIdx.x * 64;
    const int n0 = wv * 16 * NT;

    if constexpr (!AH) {
        for (int i = t; i < 2048; i += 256) {
            int r = i >> 5, c4 = i & 31;
            int gr = row0 + r;
            float4 v = make_float4(0.f, 0.f, 0.f, 0.f);
            if (gr < N) v = ((const float4*)A)[(size_t)gr * 32 + c4];
            ushort4 hi, lo;
            hi.x = f2bf(v.x); lo.x = f2bf(v.x - bf2f(hi.x));
            hi.y = f2bf(v.y); lo.y = f2bf(v.y - bf2f(hi.y));
            hi.z = f2bf(v.z); lo.z = f2bf(v.z - bf2f(hi.z));
            hi.w = f2bf(v.w); lo.w = f2bf(v.w - bf2f(hi.w));
            int idx = (r * 128 + c4 * 4) ^ ((r & 7) << 3);
            *(ushort4*)&Xhi[idx] = hi;
            *(ushort4*)&Xlo[idx] = lo;
        }
    }
    __syncthreads();

    f32x4 acc[4][NT];
#pragma unroll
    for (int mt = 0; mt < 4; mt++)
#pragma unroll
        for (int nt = 0; nt < NT; nt++) acc[mt][nt] = (f32x4){0.f, 0.f, 0.f, 0.f};

#pragma unroll
    for (int ks = 0; ks < 4; ks++) {
        bf16x8 ah[4], al[4];
#pragma unroll
        for (int mt = 0; mt < 4; mt++) {
            int row = mt * 16 + l15;
            int idx = (row * 128 + ks * 32 + lhi * 8) ^ ((row & 7) << 3);
            ah[mt] = *(const bf16x8*)&Xhi[idx];
            al[mt] = *(const bf16x8*)&Xlo[idx];
        }
#pragma unroll
        for (int nt = 0; nt < NT; nt++) {
            size_t wo = (size_t)(n0 + nt * 16 + l15) * 128 + ks * 32 + lhi * 8;
            bf16x8 bh = *(const bf16x8*)&Wth[wo];
            bf16x8 bl = *(const bf16x8*)&Wtl[wo];
#pragma unroll
            for (int mt = 0; mt < 4; mt++) {
                acc[mt][nt] = __builtin_amdgcn_mfma_f32_16x16x32_bf16(ah[mt], bh, acc[mt][nt], 0, 0, 0);
                acc[mt][nt] = __builtin_amdgcn_mfma_f32_16x16x32_bf16(ah[mt], bl, acc[mt][nt], 0, 0, 0);
                acc[mt][nt] = __builtin_amdgcn_mfma_f32_16x16x32_bf16(al[mt], bh, acc[mt][nt], 0, 0, 0);
            }
        }
    }
#pragma unroll
    for (int mt = 0; mt < 4; mt++) {
#pragma unroll
        for (int j = 0; j < 4; j++) {
            int gr = row0 + mt * 16 + lhi * 4 + j;
            if (gr < N) {
#pragma unroll
                for (int nt = 0; nt < NT; nt++)
                    C16[(size_t)gr * NCOLS + n0 + nt * 16 + l15] = f2h(acc[mt][nt][j]);
            }
        }
    }
    if constexpr (NT == 2) {
        // fused attdot, H=4: head wv = cols [n0, n0+32)
        float as0 = att_s[n0 + l15],       ad0 = att_d[n0 + l15];
        float as1v = att_s[n0 + 16 + l15], ad1v = att_d[n0 + 16 + l15];
#pragma unroll
        for (int mt = 0; mt < 4; mt++) {
#pragma unroll
            for (int j = 0; j < 4; j++) {
                float ps = acc[mt][0][j] * as0 + acc[mt][1][j] * as1v;
                float pd = acc[mt][0][j] * ad0 + acc[mt][1][j] * ad1v;
#pragma unroll
                for (int o = 1; o < 16; o <<= 1) {
                    ps += __shfl_xor(ps, o);
                    pd += __shfl_xor(pd, o);
                }
                if (l15 == 0) {
                    int gr = row0 + mt * 16 + lhi * 4 + j;
                    if (gr < N) {
                        as_out[gr * 4 + wv] = ps;
                        ad_out[gr * 4 + wv] = pd;
                    }
                }
            }
        }
    }
}

// ---------------------------------------------------------------------------
// bfill: one block per bucket (unchanged from round 14).
// ---------------------------------------------------------------------------
__global__ void bfill(const uint2* __restrict__ ebuf, const int* __restrict__ bcnt,
                      int* __restrict__ rowptr, int* __restrict__ esrc,
                      int N, int NB, int E) {
    __shared__ int cnt[512];
    __shared__ int lds[256];
    __shared__ int ebase;
    int b = blockIdx.x, t = threadIdx.x;
    int n0 = b << 9;
    cnt[t] = 0; cnt[t + 256] = 0;
    int v = (t < NB) ? bcnt[t] : 0;
    lds[t] = v;
    __syncthreads();
    int val = v;
    for (int o = 1; o < 256; o <<= 1) {
        int other = (t >= o) ? lds[t - o] : 0;
        __syncthreads();
        val += other; lds[t] = val;
        __syncthreads();
    }
    if (t == b) ebase = val - v;
    __syncthreads();
    int e0 = ebase;
    int mycnt = bcnt[b];
    const uint2* eb = ebuf + (size_t)b * ESTRIDE;
    for (int i = t; i < mycnt; i += 256)
        atomicAdd(&cnt[eb[i].y & 511], 1);
    __syncthreads();
    int c0 = cnt[2 * t], c1 = cnt[2 * t + 1];
    int s = c0 + c1;
    lds[t] = s;
    __syncthreads();
    int val2 = s;
    for (int o = 1; o < 256; o <<= 1) {
        int other = (t >= o) ? lds[t - o] : 0;
        __syncthreads();
        val2 += other; lds[t] = val2;
        __syncthreads();
    }
    int p = val2 - s;
    int nrem = N - n0;
    if (2 * t < nrem)     rowptr[n0 + 2 * t]     = e0 + p;
    if (2 * t + 1 < nrem) rowptr[n0 + 2 * t + 1] = e0 + p + c0;
    cnt[2 * t] = p; cnt[2 * t + 1] = p + c0;
    __syncthreads();
    for (int i = t; i < mycnt; i += 256) {
        uint2 ed = eb[i];
        int r = atomicAdd(&cnt[ed.y & 511], 1);
        esrc[e0 + r] = (int)ed.x;
    }
    if (b == 0 && t == 0) rowptr[N] = E;
}

// ---------------------------------------------------------------------------
// Layer-1 aggregation + FUSED layer-2 projection. Per node: chunk-32 gather
// (round-13 structure), then epilogue: out1 row (bias+ReLU, fp16) -> per-wave
// LDS rowbuf; all 64 lanes compute one h2 channel each as 64 fdot2 against
// LDS-staged W2 (stride 130 -> 2-way bank aliasing, free); h16b written
// coalesced; as2/ad2 shuffle-reduced in-wave. out1h never materialized.
// ---------------------------------------------------------------------------
__launch_bounds__(256)
__global__ void aggregate1(const ushort* __restrict__ h16,
                           const float* __restrict__ as1, const float* __restrict__ ad1,
                           const int* __restrict__ rowptr, const int* __restrict__ esrc,
                           const float* __restrict__ b1,
                           const ushort* __restrict__ W2t,
                           const float* __restrict__ att_s2, const float* __restrict__ att_d2,
                           ushort* __restrict__ h16b, float* __restrict__ as2,
                           float* __restrict__ ad2, int N) {
    __shared__ ushort W2lds[64 * 130];   // 16.6 KB
    __shared__ ushort rowbuf[4][128];
    __shared__ ushort wbuf[4][4 * 40];
    __shared__ int    sbuf[4][32];
    int wid = threadIdx.x >> 6, lane = threadIdx.x & 63;
    // stage W2 (all threads; before any early exit)
    for (int i = threadIdx.x; i < 64 * 130; i += 256) W2lds[i] = W2t[i];
    __syncthreads();

    int node = blockIdx.x * 4 + wid;
    if (node >= N) return;
    float4 asn = *(const float4*)&as1[node * 4];
    float4 adn = *(const float4*)&ad1[node * 4];
    float atts2v = att_s2[lane], attd2v = att_d2[lane];
    float4 selfw = exp4(leaky4(add4(asn, adn)));
    int start = rowptr[node], end = rowptr[node + 1];

    int eidx = lane & 15, hd = lane >> 4;     // phase-1: edges eidx, eidx+16
    float adh1 = pick4(adn, hd);
    int q = lane >> 4, c = lane & 15;         // phase-2: group q, chans 8c..
    int hh = c >> 2;
    float esum = 0.f;
    float acc[8] = {0.f, 0.f, 0.f, 0.f, 0.f, 0.f, 0.f, 0.f};

    for (int base = start; base < end; base += 32) {
        int cnt = end - base; if (cnt > 32) cnt = 32;
        int e1i = eidx, e2i = eidx + 16;
        int s1 = 0, s2 = 0; float w1 = 0.f, w2 = 0.f;
        if (e1i < cnt) s1 = esrc[base + e1i];
        if (e2i < cnt) s2 = esrc[base + e2i];
        if (e1i < cnt) w1 = __expf(leakys(as1[s1 * 4 + hd] + adh1));
        if (e2i < cnt) w2 = __expf(leakys(as1[s2 * 4 + hd] + adh1));
        esum += w1 + w2;
        wbuf[wid][hd * 40 + e1i] = f2h(w1);
        wbuf[wid][hd * 40 + e2i] = f2h(w2);
        if (hd == 0) { sbuf[wid][e1i] = s1; sbuf[wid][e2i] = s2; }
#pragma unroll 4
        for (int i = 0; i < cnt; i += 8) {
            int i1 = i + 2 * q;
            int2 ss = *(const int2*)&sbuf[wid][i1];
            half2v wp = u2h2(*(const ushort2*)&wbuf[wid][hh * 40 + i1]);
            half8 hv1 = *(const half8*)&h16[(size_t)ss.x * 128 + c * 8];
            half8 hv2 = *(const half8*)&h16[(size_t)ss.y * 128 + c * 8];
#pragma unroll
            for (int j = 0; j < 8; j++) {
                half2v hp = {hv1[j], hv2[j]};
                acc[j] = __builtin_amdgcn_fdot2(hp, wp, acc[j], false);
            }
        }
    }
#pragma unroll
    for (int o = 1; o < 16; o <<= 1) esum += __shfl_xor(esum, o);
    float denom = __shfl(esum, hh << 4) + pick4(selfw, hh) + 1e-16f;
    float inv = 1.f / denom;
    float sw = pick4(selfw, hh);

#pragma unroll
    for (int j = 0; j < 8; j++) {
        acc[j] += __shfl_xor(acc[j], 16);
        acc[j] += __shfl_xor(acc[j], 32);
    }
    if (q == 0) {
        half8 hs = *(const half8*)&h16[(size_t)node * 128 + c * 8];
        const float* bb = &b1[c * 8];
        half8 ov;
#pragma unroll
        for (int j = 0; j < 8; j++) {
            float oj = fmaxf((acc[j] + sw * (float)hs[j]) * inv + bb[j], 0.f);
            ov[j] = (_Float16)oj;
        }
        *(half8*)&rowbuf[wid][c * 8] = ov;    // to LDS, not global
    }
    // fused layer-2 projection: lane = output channel (wave-synchronous LDS)
    {
        const half2v* rp = (const half2v*)&rowbuf[wid][0];
        const half2v* wp = (const half2v*)&W2lds[lane * 130];
        float o2 = 0.f;
#pragma unroll
        for (int k2 = 0; k2 < 64; k2++)
            o2 = __builtin_amdgcn_fdot2(rp[k2], wp[k2], o2, false);
        h16b[(size_t)node * 64 + lane] = f2h(o2);
        float ps = o2 * atts2v;
        float pd = o2 * attd2v;
#pragma unroll
        for (int o = 1; o < 64; o <<= 1) {
            ps += __shfl_xor(ps, o);
            pd += __shfl_xor(pd, o);
        }
        if (lane == 0) { as2[node] = ps; ad2[node] = pd; }
    }
}

// ---------------------------------------------------------------------------
// Layer-2 aggregation (H=1, C=64) — unchanged round-13 body.
// ---------------------------------------------------------------------------
__launch_bounds__(256)
__global__ void aggregate2(const ushort* __restrict__ h16,
                           const float* __restrict__ as2, const float* __restrict__ ad2,
                           const int* __restrict__ rowptr, const int* __restrict__ esrc,
                           const float* __restrict__ b2, float* __restrict__ out, int N) {
    __shared__ ushort wbuf[4][64];
    __shared__ int    sbuf[4][64];
    int wid = threadIdx.x >> 6, lane = threadIdx.x & 63;
    int node = blockIdx.x * 4 + wid;
    if (node >= N) return;
    float adn = ad2[node];
    float selfw = __expf(leakys(as2[node] + adn));
    int start = rowptr[node], end = rowptr[node + 1];

    int q = lane >> 3, c = lane & 7;
    float ssum = 0.f;
    float acc[8] = {0.f, 0.f, 0.f, 0.f, 0.f, 0.f, 0.f, 0.f};

    for (int base = start; base < end; base += 64) {
        int cnt = end - base; if (cnt > 64) cnt = 64;
        int s = 0; float w = 0.f;
        if (lane < cnt) {
            s = esrc[base + lane];
            w = __expf(leakys(as2[s] + adn));
        }
        ssum += w;
        wbuf[wid][lane] = f2h(w);
        sbuf[wid][lane] = s;
#pragma unroll 4
        for (int i = 0; i < cnt; i += 16) {
            int i1 = i + 2 * q;
            int2 ss = *(const int2*)&sbuf[wid][i1];
            half2v wp = u2h2(*(const ushort2*)&wbuf[wid][i1]);
            half8 hv1 = *(const half8*)&h16[(size_t)ss.x * 64 + c * 8];
            half8 hv2 = *(const half8*)&h16[(size_t)ss.y * 64 + c * 8];
#pragma unroll
            for (int j = 0; j < 8; j++) {
                half2v hp = {hv1[j], hv2[j]};
                acc[j] = __builtin_amdgcn_fdot2(hp, wp, acc[j], false);
            }
        }
    }
#pragma unroll
    for (int o = 1; o < 64; o <<= 1) ssum += __shfl_xor(ssum, o);
    float inv = 1.f / (ssum + selfw + 1e-16f);

#pragma unroll
    for (int j = 0; j < 8; j++) {
        acc[j] += __shfl_xor(acc[j], 8);
        acc[j] += __shfl_xor(acc[j], 16);
        acc[j] += __shfl_xor(acc[j], 32);
    }
    if (lane < 8) {
        half8 hs = *(const half8*)&h16[(size_t)node * 64 + c * 8];
        const float* bb = &b2[c * 8];
        float o[8];
#pragma unroll
        for (int j = 0; j < 8; j++)
            o[j] = (acc[j] + selfw * (float)hs[j]) * inv + bb[j];
        float4* op = (float4*)&out[(size_t)node * 64 + c * 8];
        op[0] = make_float4(o[0], o[1], o[2], o[3]);
        op[1] = make_float4(o[4], o[5], o[6], o[7]);
    }
}

// ---------------------------------------------------------------------------
extern "C" void kernel_launch(void* const* d_in, const int* in_sizes, int n_in,
                              void* d_out, int out_size, void* d_ws, size_t ws_size,
                              hipStream_t stream) {
    const float* x      = (const float*)d_in[0];
    const int*   ei     = (const int*)d_in[1];
    const float* W1     = (const float*)d_in[2];
    const float* att_s1 = (const float*)d_in[3];
    const float* att_d1 = (const float*)d_in[4];
    const float* b1     = (const float*)d_in[5];
    const float* W2     = (const float*)d_in[6];
    const float* att_s2 = (const float*)d_in[7];
    const float* att_d2 = (const float*)d_in[8];
    const float* b2     = (const float*)d_in[9];

    const int N = in_sizes[0] / 128;
    const int E = in_sizes[1] / 2;
    const int NB = (N + 511) >> 9;         // buckets of 512 dst nodes (<=256)

    char* ws = (char*)d_ws;
    size_t off = 0;
    auto alloc = [&](size_t bytes) -> void* {
        off = (off + 255) & ~(size_t)255;
        void* p = ws + off;
        off += bytes;
        return p;
    };
    ushort* h16   = (ushort*)alloc((size_t)N * 128 * 2);   // layer-1 rows (fp16)
    ushort* h16b  = (ushort*)alloc((size_t)N * 64 * 2);    // layer-2 rows (fp16)
    uint2*  ebuf  = (uint2*)alloc((size_t)256 * ESTRIDE * 8);  // scatter staging
    float* as1    = (float*)alloc((size_t)N * 4 * 4);
    float* ad1    = (float*)alloc((size_t)N * 4 * 4);
    float* as2    = (float*)alloc((size_t)N * 4);
    float* ad2    = (float*)alloc((size_t)N * 4);
    int*   rowptr = (int*)alloc((size_t)(N + 1) * 4);
    int*   esrc   = (int*)alloc((size_t)E * 4);
    int*   bcursor = (int*)alloc(256 * 4);
    ushort* Wt1h  = (ushort*)alloc(128 * 128 * 2);
    ushort* Wt1l  = (ushort*)alloc(128 * 128 * 2);
    ushort* W2t   = (ushort*)alloc(64 * 130 * 2);

    const int* srcIdx = ei;
    const int* dstIdx = ei + E;

    hipMemsetAsync(bcursor, 0, 256 * 4, stream);

    prep_w<<<64, 256, 0, stream>>>(W1, Wt1h, Wt1l, 128);
    prep_w2h<<<32, 256, 0, stream>>>(W2, W2t);

    const int nGemm1 = (N + 63) / 64;
    const int nScat  = (E + 4095) / 4096;
    gemm_mfma<128, false><<<nGemm1 + nScat, 256, 0, stream>>>(
        x, nullptr, Wt1h, Wt1l, h16, att_s1, att_d1, as1, ad1, N,
        srcIdx, dstIdx, bcursor, ebuf, E, nGemm1);

    bfill<<<NB, 256, 0, stream>>>(ebuf, bcursor, rowptr, esrc, N, NB, E);

    aggregate1<<<(N + 3) / 4, 256, 0, stream>>>(h16, as1, ad1, rowptr, esrc, b1,
                                                W2t, att_s2, att_d2,
                                                h16b, as2, ad2, N);

    aggregate2<<<(N + 3) / 4, 256, 0, stream>>>(h16b, as2, ad2, rowptr, esrc,
                                                b2, (float*)d_out, N);
}

// Round 16
// 222.563 us; speedup vs baseline: 1.0798x; 1.0798x over previous
//
#include <hip/hip_runtime.h>
#include <hip/hip_bf16.h>

#define DEV static __device__ __forceinline__

typedef __attribute__((ext_vector_type(4))) float f32x4;
typedef __attribute__((ext_vector_type(8))) short bf16x8;
typedef __attribute__((ext_vector_type(8))) _Float16 half8;
typedef __attribute__((ext_vector_type(2))) _Float16 half2v;
typedef __attribute__((ext_vector_type(8))) unsigned short u16x8;

#define ESTRIDE 10240   // edges per bucket region in ebuf (Poisson(6250)+45sd)

DEV float leakys(float v) { return v > 0.f ? v : 0.2f * v; }
DEV float4 add4(float4 a, float4 b) { return make_float4(a.x+b.x, a.y+b.y, a.z+b.z, a.w+b.w); }
DEV float4 leaky4(float4 v) { return make_float4(leakys(v.x), leakys(v.y), leakys(v.z), leakys(v.w)); }
DEV float4 exp4(float4 v) { return make_float4(__expf(v.x), __expf(v.y), __expf(v.z), __expf(v.w)); }
DEV float pick4(float4 v, int i) {
    float r = v.x;
    r = (i == 1) ? v.y : r;
    r = (i == 2) ? v.z : r;
    r = (i == 3) ? v.w : r;
    return r;
}

DEV ushort f2bf(float f) {
    union { float f; unsigned u; } v; v.f = f;
    unsigned u = v.u;
    unsigned r = (u + 0x7FFFu + ((u >> 16) & 1u)) >> 16;   // RNE
    return (ushort)r;
}
DEV float bf2f(ushort h) {
    union { unsigned u; float f; } v; v.u = ((unsigned)h) << 16;
    return v.f;
}
DEV ushort f2h(float f) {
    union { _Float16 h; ushort u; } v;
    v.h = (_Float16)f;
    return v.u;
}
DEV half2v u2h2(ushort2 u) {
    union { ushort2 u; half2v h; } v; v.u = u;
    return v.h;
}

// ---------------------------------------------------------------------------
// One-time W prep: W[K=128][NC] f32 -> transposed bf16 hi/lo  Wt[n][k].
// ---------------------------------------------------------------------------
__global__ void prep_w(const float* __restrict__ W, ushort* __restrict__ Wth,
                       ushort* __restrict__ Wtl, int NC) {
    int i = blockIdx.x * 256 + threadIdx.x;
    if (i >= 128 * NC) return;
    int k = i / NC, n = i % NC;
    float v = W[i];
    ushort hi = f2bf(v);
    ushort lo = f2bf(v - bf2f(hi));
    Wth[n * 128 + k] = hi;
    Wtl[n * 128 + k] = lo;
}

// ---------------------------------------------------------------------------
// MFMA GEMM: C[N][NCOLS] = A[N][128] @ W[128][NCOLS], split-bf16 (3 MFMA).
// A is f32 (AH=false) or fp16 (AH=true). Output: fp16 C16 only.
// Fused attention dots (see NT==2 / else branches).
// Heterogeneous grid: blocks >= nGemmBlocks run an independent bucket
// SCATTER (4096-edge tile -> per-bucket fixed-stride ebuf regions, cursors
// local to each bucket) to overlap the whole CSR scatter with the GEMM.
// ---------------------------------------------------------------------------
template <int NCOLS, bool AH>
__launch_bounds__(256, 2)
__global__ void gemm_mfma(const float* __restrict__ A, const ushort* __restrict__ A16,
                          const ushort* __restrict__ Wth, const ushort* __restrict__ Wtl,
                          ushort* __restrict__ C16,
                          const float* __restrict__ att_s, const float* __restrict__ att_d,
                          float* __restrict__ as_out, float* __restrict__ ad_out, int N,
                          const int* __restrict__ srcIdx, const int* __restrict__ dstIdx,
                          int* __restrict__ bcursor, uint2* __restrict__ ebuf,
                          int E, int nGemmBlocks) {
    constexpr int NT = NCOLS / 64;          // 16-wide n-tiles per wave
    __shared__ ushort Xhi[64 * 128];
    __shared__ ushort Xlo[64 * 128];
    __shared__ float pbs[64][4];
    __shared__ float pbd[64][4];
    const int t = threadIdx.x;

    if (blockIdx.x >= nGemmBlocks) {       // ---- fused bscatter path ----
        __shared__ int hist[256];
        __shared__ int gofs[256];
        hist[t] = 0;
        __syncthreads();
        int blk = blockIdx.x - nGemmBlocks;
        int e0 = blk * 4096;
        int e1 = min(E, e0 + 4096);
        for (int e = e0 + t; e < e1; e += 256)
            atomicAdd(&hist[dstIdx[e] >> 9], 1);
        __syncthreads();
        int h = hist[t];
        if (h) gofs[t] = atomicAdd(&bcursor[t], h);
        __syncthreads();
        hist[t] = 0;
        __syncthreads();
        for (int e = e0 + t; e < e1; e += 256) {
            int d = dstIdx[e];
            int b = d >> 9;
            int r = atomicAdd(&hist[b], 1);
            uint2 v; v.x = (unsigned)srcIdx[e]; v.y = (unsigned)d;
            ebuf[(size_t)b * ESTRIDE + gofs[b] + r] = v;
        }
        return;
    }

    const int wv = t >> 6, l = t & 63;
    const int l15 = l & 15, lhi = l >> 4;
    const int row0 = blockIdx.x * 64;
    const int n0 = wv * 16 * NT;

    if constexpr (!AH) {
        for (int i = t; i < 2048; i += 256) {
            int r = i >> 5, c4 = i & 31;
            int gr = row0 + r;
            float4 v = make_float4(0.f, 0.f, 0.f, 0.f);
            if (gr < N) v = ((const float4*)A)[(size_t)gr * 32 + c4];
            ushort4 hi, lo;
            hi.x = f2bf(v.x); lo.x = f2bf(v.x - bf2f(hi.x));
            hi.y = f2bf(v.y); lo.y = f2bf(v.y - bf2f(hi.y));
            hi.z = f2bf(v.z); lo.z = f2bf(v.z - bf2f(hi.z));
            hi.w = f2bf(v.w); lo.w = f2bf(v.w - bf2f(hi.w));
            int idx = (r * 128 + c4 * 4) ^ ((r & 7) << 3);
            *(ushort4*)&Xhi[idx] = hi;
            *(ushort4*)&Xlo[idx] = lo;
        }
    } else {
        for (int i = t; i < 1024; i += 256) {
            int r = i >> 4, c8 = i & 15;
            int gr = row0 + r;
            half8 v = (half8){0, 0, 0, 0, 0, 0, 0, 0};
            if (gr < N) v = *(const half8*)&A16[(size_t)gr * 128 + c8 * 8];
            u16x8 hi, lo;
#pragma unroll
            for (int j = 0; j < 8; j++) {
                float f = (float)v[j];
                ushort hb = f2bf(f);
                hi[j] = hb;
                lo[j] = f2bf(f - bf2f(hb));
            }
            int idx = (r * 128 + c8 * 8) ^ ((r & 7) << 3);
            *(u16x8*)&Xhi[idx] = hi;
            *(u16x8*)&Xlo[idx] = lo;
        }
    }
    __syncthreads();

    f32x4 acc[4][NT];
#pragma unroll
    for (int mt = 0; mt < 4; mt++)
#pragma unroll
        for (int nt = 0; nt < NT; nt++) acc[mt][nt] = (f32x4){0.f, 0.f, 0.f, 0.f};

#pragma unroll
    for (int ks = 0; ks < 4; ks++) {
        bf16x8 ah[4], al[4];
#pragma unroll
        for (int mt = 0; mt < 4; mt++) {
            int row = mt * 16 + l15;
            int idx = (row * 128 + ks * 32 + lhi * 8) ^ ((row & 7) << 3);
            ah[mt] = *(const bf16x8*)&Xhi[idx];
            al[mt] = *(const bf16x8*)&Xlo[idx];
        }
#pragma unroll
        for (int nt = 0; nt < NT; nt++) {
            size_t wo = (size_t)(n0 + nt * 16 + l15) * 128 + ks * 32 + lhi * 8;
            bf16x8 bh = *(const bf16x8*)&Wth[wo];
            bf16x8 bl = *(const bf16x8*)&Wtl[wo];
#pragma unroll
            for (int mt = 0; mt < 4; mt++) {
                acc[mt][nt] = __builtin_amdgcn_mfma_f32_16x16x32_bf16(ah[mt], bh, acc[mt][nt], 0, 0, 0);
                acc[mt][nt] = __builtin_amdgcn_mfma_f32_16x16x32_bf16(ah[mt], bl, acc[mt][nt], 0, 0, 0);
                acc[mt][nt] = __builtin_amdgcn_mfma_f32_16x16x32_bf16(al[mt], bh, acc[mt][nt], 0, 0, 0);
            }
        }
    }
#pragma unroll
    for (int mt = 0; mt < 4; mt++) {
#pragma unroll
        for (int j = 0; j < 4; j++) {
            int gr = row0 + mt * 16 + lhi * 4 + j;
            if (gr < N) {
#pragma unroll
                for (int nt = 0; nt < NT; nt++)
                    C16[(size_t)gr * NCOLS + n0 + nt * 16 + l15] = f2h(acc[mt][nt][j]);
            }
        }
    }
    if constexpr (NT == 2) {
        // fused attdot, H=4: head wv = cols [n0, n0+32)
        float as0 = att_s[n0 + l15],       ad0 = att_d[n0 + l15];
        float as1v = att_s[n0 + 16 + l15], ad1v = att_d[n0 + 16 + l15];
#pragma unroll
        for (int mt = 0; mt < 4; mt++) {
#pragma unroll
            for (int j = 0; j < 4; j++) {
                float ps = acc[mt][0][j] * as0 + acc[mt][1][j] * as1v;
                float pd = acc[mt][0][j] * ad0 + acc[mt][1][j] * ad1v;
#pragma unroll
                for (int o = 1; o < 16; o <<= 1) {
                    ps += __shfl_xor(ps, o);
                    pd += __shfl_xor(pd, o);
                }
                if (l15 == 0) {
                    int gr = row0 + mt * 16 + lhi * 4 + j;
                    if (gr < N) {
                        as_out[gr * 4 + wv] = ps;
                        ad_out[gr * 4 + wv] = pd;
                    }
                }
            }
        }
    } else {
        // fused attdot, H=1: wave partials over 16 cols -> LDS -> combine
        float as0 = att_s[n0 + l15], ad0 = att_d[n0 + l15];
#pragma unroll
        for (int mt = 0; mt < 4; mt++) {
#pragma unroll
            for (int j = 0; j < 4; j++) {
                float ps = acc[mt][0][j] * as0;
                float pd = acc[mt][0][j] * ad0;
#pragma unroll
                for (int o = 1; o < 16; o <<= 1) {
                    ps += __shfl_xor(ps, o);
                    pd += __shfl_xor(pd, o);
                }
                if (l15 == 0) {
                    int rl = mt * 16 + lhi * 4 + j;
                    pbs[rl][wv] = ps;
                    pbd[rl][wv] = pd;
                }
            }
        }
        __syncthreads();
        if (t < 64) {
            int gr = row0 + t;
            if (gr < N) {
                as_out[gr] = pbs[t][0] + pbs[t][1] + pbs[t][2] + pbs[t][3];
                ad_out[gr] = pbd[t][0] + pbd[t][1] + pbd[t][2] + pbd[t][3];
            }
        }
    }
}

// ---------------------------------------------------------------------------
// bfill: one block per bucket. Reads final bucket cursors (= counts),
// redundantly exclusive-scans all 256 to get its global base, then LDS
// node-histogram -> scan -> rowptr + local esrc fill (same layout as before).
// ---------------------------------------------------------------------------
__global__ void bfill(const uint2* __restrict__ ebuf, const int* __restrict__ bcnt,
                      int* __restrict__ rowptr, int* __restrict__ esrc,
                      int N, int NB, int E) {
    __shared__ int cnt[512];
    __shared__ int lds[256];
    __shared__ int ebase;
    int b = blockIdx.x, t = threadIdx.x;
    int n0 = b << 9;
    cnt[t] = 0; cnt[t + 256] = 0;
    // global exclusive scan of bucket counts (redundant per block)
    int v = (t < NB) ? bcnt[t] : 0;
    lds[t] = v;
    __syncthreads();
    int val = v;
    for (int o = 1; o < 256; o <<= 1) {
        int other = (t >= o) ? lds[t - o] : 0;
        __syncthreads();
        val += other; lds[t] = val;
        __syncthreads();
    }
    if (t == b) ebase = val - v;   // exclusive prefix of this bucket
    __syncthreads();
    int e0 = ebase;
    int mycnt = bcnt[b];
    const uint2* eb = ebuf + (size_t)b * ESTRIDE;
    for (int i = t; i < mycnt; i += 256)
        atomicAdd(&cnt[eb[i].y & 511], 1);
    __syncthreads();
    int c0 = cnt[2 * t], c1 = cnt[2 * t + 1];
    int s = c0 + c1;
    lds[t] = s;
    __syncthreads();
    int val2 = s;
    for (int o = 1; o < 256; o <<= 1) {
        int other = (t >= o) ? lds[t - o] : 0;
        __syncthreads();
        val2 += other; lds[t] = val2;
        __syncthreads();
    }
    int p = val2 - s;          // exclusive prefix of this thread's pair
    int nrem = N - n0;
    if (2 * t < nrem)     rowptr[n0 + 2 * t]     = e0 + p;
    if (2 * t + 1 < nrem) rowptr[n0 + 2 * t + 1] = e0 + p + c0;
    cnt[2 * t] = p; cnt[2 * t + 1] = p + c0;   // local cursors
    __syncthreads();
    for (int i = t; i < mycnt; i += 256) {
        uint2 ed = eb[i];
        int r = atomicAdd(&cnt[ed.y & 511], 1);
        esrc[e0 + r] = (int)ed.x;
    }
    if (b == 0 && t == 0) rowptr[N] = E;
}

// ---------------------------------------------------------------------------
// Layer-1 aggregation. Chunk = 32 edges (single chain for ~99% of nodes).
// Phase 1 head-parallel: 64 lanes = 16 edges x 4 heads, TWO edges per lane,
// one exp each; fp16 weights -> [head][40-padded edge] LDS. Phase 2: 16
// lanes x 16B rows, adjacent edge pairs -> packed half2 weight + int2 src
// reads; fdot2 f32 accumulate; 4 unrolled iterations. m=0 softmax.
// ---------------------------------------------------------------------------
__launch_bounds__(256)
__global__ void aggregate1(const ushort* __restrict__ h16,
                           const float* __restrict__ as1, const float* __restrict__ ad1,
                           const int* __restrict__ rowptr, const int* __restrict__ esrc,
                           const float* __restrict__ b1, ushort* __restrict__ out1h, int N) {
    __shared__ ushort wbuf[4][4 * 40];   // [wave][head*40 + edge], 32 edges
    __shared__ int    sbuf[4][32];
    int wid = threadIdx.x >> 6, lane = threadIdx.x & 63;
    int node = blockIdx.x * 4 + wid;
    if (node >= N) return;
    float4 asn = *(const float4*)&as1[node * 4];
    float4 adn = *(const float4*)&ad1[node * 4];
    float4 selfw = exp4(leaky4(add4(asn, adn)));
    int start = rowptr[node], end = rowptr[node + 1];

    int eidx = lane & 15, hd = lane >> 4;     // phase-1: edges eidx, eidx+16
    float adh1 = pick4(adn, hd);
    int q = lane >> 4, c = lane & 15;         // phase-2: group q, chans 8c..
    int hh = c >> 2;                          // head of this lane's channels
    float esum = 0.f;                         // per-lane partial (head hd)
    float acc[8] = {0.f, 0.f, 0.f, 0.f, 0.f, 0.f, 0.f, 0.f};

    for (int base = start; base < end; base += 32) {
        int cnt = end - base; if (cnt > 32) cnt = 32;
        // phase 1: two edges per lane, one exp each; zero-fill dead slots
        int e1i = eidx, e2i = eidx + 16;
        int s1 = 0, s2 = 0; float w1 = 0.f, w2 = 0.f;
        if (e1i < cnt) s1 = esrc[base + e1i];
        if (e2i < cnt) s2 = esrc[base + e2i];
        if (e1i < cnt) w1 = __expf(leakys(as1[s1 * 4 + hd] + adh1));
        if (e2i < cnt) w2 = __expf(leakys(as1[s2 * 4 + hd] + adh1));
        esum += w1 + w2;
        wbuf[wid][hd * 40 + e1i] = f2h(w1);
        wbuf[wid][hd * 40 + e2i] = f2h(w2);
        if (hd == 0) { sbuf[wid][e1i] = s1; sbuf[wid][e2i] = s2; }
        // phase 2: 8 edges/iter, adjacent pair per group
#pragma unroll 4
        for (int i = 0; i < cnt; i += 8) {
            int i1 = i + 2 * q;
            int2 ss = *(const int2*)&sbuf[wid][i1];
            half2v wp = u2h2(*(const ushort2*)&wbuf[wid][hh * 40 + i1]);
            half8 hv1 = *(const half8*)&h16[(size_t)ss.x * 128 + c * 8];
            half8 hv2 = *(const half8*)&h16[(size_t)ss.y * 128 + c * 8];
#pragma unroll
            for (int j = 0; j < 8; j++) {
                half2v hp = {hv1[j], hv2[j]};
                acc[j] = __builtin_amdgcn_fdot2(hp, wp, acc[j], false);
            }
        }
    }
    // reduce denominator within each 16-lane head group, then broadcast
#pragma unroll
    for (int o = 1; o < 16; o <<= 1) esum += __shfl_xor(esum, o);
    float denom = __shfl(esum, hh << 4) + pick4(selfw, hh) + 1e-16f;
    float inv = 1.f / denom;
    float sw = pick4(selfw, hh);

#pragma unroll
    for (int j = 0; j < 8; j++) {
        acc[j] += __shfl_xor(acc[j], 16);
        acc[j] += __shfl_xor(acc[j], 32);
    }
    if (q == 0) {
        half8 hs = *(const half8*)&h16[(size_t)node * 128 + c * 8];
        const float* bb = &b1[c * 8];
        half8 ov;
#pragma unroll
        for (int j = 0; j < 8; j++) {
            float oj = fmaxf((acc[j] + sw * (float)hs[j]) * inv + bb[j], 0.f);
            ov[j] = (_Float16)oj;
        }
        *(half8*)&out1h[(size_t)node * 128 + c * 8] = ov;
    }
}

// ---------------------------------------------------------------------------
// Layer-2 aggregation (H=1, C=64). Chunk = 64 edges, one exp per lane.
// fp16 weights; phase 2: 8 lanes x 16B rows, adjacent edge pairs per group
// -> packed half2 weight + int2 src reads; fdot2; 4 unrolled iterations.
// ---------------------------------------------------------------------------
__launch_bounds__(256)
__global__ void aggregate2(const ushort* __restrict__ h16,
                           const float* __restrict__ as2, const float* __restrict__ ad2,
                           const int* __restrict__ rowptr, const int* __restrict__ esrc,
                           const float* __restrict__ b2, float* __restrict__ out, int N) {
    __shared__ ushort wbuf[4][64];
    __shared__ int    sbuf[4][64];
    int wid = threadIdx.x >> 6, lane = threadIdx.x & 63;
    int node = blockIdx.x * 4 + wid;
    if (node >= N) return;
    float adn = ad2[node];
    float selfw = __expf(leakys(as2[node] + adn));
    int start = rowptr[node], end = rowptr[node + 1];

    int q = lane >> 3, c = lane & 7;    // group q; channels 8c..8c+7
    float ssum = 0.f;
    float acc[8] = {0.f, 0.f, 0.f, 0.f, 0.f, 0.f, 0.f, 0.f};

    for (int base = start; base < end; base += 64) {
        int cnt = end - base; if (cnt > 64) cnt = 64;
        // phase 1: one exp per lane; zero-fill dead slots
        int s = 0; float w = 0.f;
        if (lane < cnt) {
            s = esrc[base + lane];
            w = __expf(leakys(as2[s] + adn));
        }
        ssum += w;
        wbuf[wid][lane] = f2h(w);
        sbuf[wid][lane] = s;
        // phase 2: 16 edges/iter, adjacent pair per group
#pragma unroll 4
        for (int i = 0; i < cnt; i += 16) {
            int i1 = i + 2 * q;
            int2 ss = *(const int2*)&sbuf[wid][i1];
            half2v wp = u2h2(*(const ushort2*)&wbuf[wid][i1]);
            half8 hv1 = *(const half8*)&h16[(size_t)ss.x * 64 + c * 8];
            half8 hv2 = *(const half8*)&h16[(size_t)ss.y * 64 + c * 8];
#pragma unroll
            for (int j = 0; j < 8; j++) {
                half2v hp = {hv1[j], hv2[j]};
                acc[j] = __builtin_amdgcn_fdot2(hp, wp, acc[j], false);
            }
        }
    }
#pragma unroll
    for (int o = 1; o < 64; o <<= 1) ssum += __shfl_xor(ssum, o);
    float inv = 1.f / (ssum + selfw + 1e-16f);

#pragma unroll
    for (int j = 0; j < 8; j++) {
        acc[j] += __shfl_xor(acc[j], 8);
        acc[j] += __shfl_xor(acc[j], 16);
        acc[j] += __shfl_xor(acc[j], 32);
    }
    if (lane < 8) {
        half8 hs = *(const half8*)&h16[(size_t)node * 64 + c * 8];
        const float* bb = &b2[c * 8];
        float o[8];
#pragma unroll
        for (int j = 0; j < 8; j++)
            o[j] = (acc[j] + selfw * (float)hs[j]) * inv + bb[j];
        float4* op = (float4*)&out[(size_t)node * 64 + c * 8];
        op[0] = make_float4(o[0], o[1], o[2], o[3]);
        op[1] = make_float4(o[4], o[5], o[6], o[7]);
    }
}

// ---------------------------------------------------------------------------
extern "C" void kernel_launch(void* const* d_in, const int* in_sizes, int n_in,
                              void* d_out, int out_size, void* d_ws, size_t ws_size,
                              hipStream_t stream) {
    const float* x      = (const float*)d_in[0];
    const int*   ei     = (const int*)d_in[1];
    const float* W1     = (const float*)d_in[2];
    const float* att_s1 = (const float*)d_in[3];
    const float* att_d1 = (const float*)d_in[4];
    const float* b1     = (const float*)d_in[5];
    const float* W2     = (const float*)d_in[6];
    const float* att_s2 = (const float*)d_in[7];
    const float* att_d2 = (const float*)d_in[8];
    const float* b2     = (const float*)d_in[9];

    const int N = in_sizes[0] / 128;
    const int E = in_sizes[1] / 2;
    const int NB = (N + 511) >> 9;         // buckets of 512 dst nodes (<=256)

    char* ws = (char*)d_ws;
    size_t off = 0;
    auto alloc = [&](size_t bytes) -> void* {
        off = (off + 255) & ~(size_t)255;
        void* p = ws + off;
        off += bytes;
        return p;
    };
    ushort* h16   = (ushort*)alloc((size_t)N * 128 * 2);   // layer-1 rows (fp16)
    ushort* out1h = (ushort*)alloc((size_t)N * 128 * 2);   // layer-1 output (fp16)
    float* as1    = (float*)alloc((size_t)N * 4 * 4);
    float* ad1    = (float*)alloc((size_t)N * 4 * 4);
    float* as2    = (float*)alloc((size_t)N * 4);
    float* ad2    = (float*)alloc((size_t)N * 4);
    int*   rowptr = (int*)alloc((size_t)(N + 1) * 4);
    int*   esrc   = (int*)alloc((size_t)E * 4);
    int*   bcursor = (int*)alloc(256 * 4);
    ushort* Wt1h  = (ushort*)alloc(128 * 128 * 2);
    ushort* Wt1l  = (ushort*)alloc(128 * 128 * 2);
    ushort* Wt2h  = (ushort*)alloc(64 * 128 * 2);
    ushort* Wt2l  = (ushort*)alloc(64 * 128 * 2);
    ushort* h16b = h16;           // layer-2 rows reuse h16 (dead after aggregate1)
    uint2* ebuf = (uint2*)out1h;  // 256*ESTRIDE*8 = 21 MB <= N*256 B; consumed
                                  // by bfill before aggregate1 writes out1h

    const int* srcIdx = ei;
    const int* dstIdx = ei + E;

    hipMemsetAsync(bcursor, 0, 256 * 4, stream);

    prep_w<<<64, 256, 0, stream>>>(W1, Wt1h, Wt1l, 128);
    prep_w<<<32, 256, 0, stream>>>(W2, Wt2h, Wt2l, 64);

    const int nGemm1 = (N + 63) / 64;
    const int nScat  = (E + 4095) / 4096;
    gemm_mfma<128, false><<<nGemm1 + nScat, 256, 0, stream>>>(
        x, nullptr, Wt1h, Wt1l, h16, att_s1, att_d1, as1, ad1, N,
        srcIdx, dstIdx, bcursor, ebuf, E, nGemm1);

    bfill<<<NB, 256, 0, stream>>>(ebuf, bcursor, rowptr, esrc, N, NB, E);

    aggregate1<<<(N + 3) / 4, 256, 0, stream>>>(h16, as1, ad1, rowptr, esrc,
                                                b1, out1h, N);

    const int nGemm2 = (N + 63) / 64;
    gemm_mfma<64, true><<<nGemm2, 256, 0, stream>>>(
        nullptr, out1h, Wt2h, Wt2l, h16b, att_s2, att_d2, as2, ad2, N,
        nullptr, nullptr, nullptr, nullptr, 0, nGemm2);

    aggregate2<<<(N + 3) / 4, 256, 0, stream>>>(h16b, as2, ad2, rowptr, esrc,
                                                b2, (float*)d_out, N);
}